// Round 3
// baseline (898.091 us; speedup 1.0000x reference)
//
#include <hip/hip_runtime.h>
#include <stdint.h>

#define NN 50000
#define NE 600000
#define CH 128
#define RT 2                      // row-tiles (of 16 edges) per wave -> 32 edges/wave

typedef __attribute__((ext_vector_type(8))) short short8;   // 8 bf16
typedef __attribute__((ext_vector_type(4))) float f32x4;

__device__ __forceinline__ ushort f2bf(float f) {
  union { float f; uint32_t u; } v; v.f = f;
  uint32_t u = v.u;
  return (ushort)((u + 0x7FFFu + ((u >> 16) & 1u)) >> 16);  // RNE, inputs finite
}
__device__ __forceinline__ float bf2f(uint32_t u16) {
  union { uint32_t u; float f; } t; t.u = u16 << 16; return t.f;
}

// ---- prep: transpose weights to [N][K] bf16 in ws ----
// layout in wt (ushort): ew1T[128][384] @0, ew2T[128][128] @49152, nw1T[128][256] @65536, nw2T[128][128] @98304
__global__ void prep_weights_k(const float* __restrict__ ew1, const float* __restrict__ ew2,
                               const float* __restrict__ nw1, const float* __restrict__ nw2,
                               ushort* __restrict__ wt) {
  int i = blockIdx.x * 256 + threadIdx.x;
  if (i < 49152) {
    int n = i / 384, k = i - n * 384;
    wt[i] = f2bf(ew1[k * 128 + n]);
  } else if (i < 65536) {
    int j = i - 49152; int n = j >> 7, k = j & 127;
    wt[i] = f2bf(ew2[k * 128 + n]);
  } else if (i < 98304) {
    int j = i - 65536; int n = j >> 8, k = j & 255;
    wt[i] = f2bf(nw1[k * 128 + n]);
  } else if (i < 114688) {
    int j = i - 98304; int n = j >> 7, k = j & 127;
    wt[i] = f2bf(nw2[k * 128 + n]);
  }
}

__global__ void convert_x_k(const float* __restrict__ x, ushort* __restrict__ xb) {
  int i = blockIdx.x * 256 + threadIdx.x;          // over NN*CH/4 float4s
  if (i >= NN * CH / 4) return;
  const float4 f = reinterpret_cast<const float4*>(x)[i];
  ushort4 r;
  r.x = f2bf(f.x); r.y = f2bf(f.y); r.z = f2bf(f.z); r.w = f2bf(f.w);
  reinterpret_cast<ushort4*>(xb)[i] = r;
}

__global__ void histogram_k(const int* __restrict__ ei, unsigned* __restrict__ cnt) {
  int e = blockIdx.x * 256 + threadIdx.x;
  if (e < NE) atomicAdd(&cnt[ei[e]], 1u);
}

// single-block exclusive prefix sum over cnt[NN] -> start[NN]
__global__ void scan_k(const unsigned* __restrict__ cnt, unsigned* __restrict__ start) {
  __shared__ unsigned s[1024];
  const int CHUNK = (NN + 1023) / 1024;            // 49
  int t = threadIdx.x;
  int lo = t * CHUNK, hi = lo + CHUNK < NN ? lo + CHUNK : NN;
  unsigned sum = 0;
  for (int i = lo; i < hi; ++i) sum += cnt[i];
  s[t] = sum;
  __syncthreads();
  for (int off = 1; off < 1024; off <<= 1) {       // Hillis-Steele inclusive
    unsigned v = (t >= off) ? s[t - off] : 0u;
    __syncthreads();
    s[t] += v;
    __syncthreads();
  }
  unsigned run = t ? s[t - 1] : 0u;
  for (int i = lo; i < hi; ++i) { start[i] = run; run += cnt[i]; }
}

// build per-node edge lists (CSR): eidx[start[r] .. start[r]+cnt[r])
__global__ void scatter_k(const int* __restrict__ ei, const unsigned* __restrict__ start,
                          unsigned* __restrict__ cursor, unsigned* __restrict__ eidx) {
  int e = blockIdx.x * 256 + threadIdx.x;
  if (e < NE) {
    int r = ei[e];
    unsigned pos = start[r] + atomicAdd(&cursor[r], 1u);
    eidx[pos] = e;
  }
}

// one MFMA k-step across 8 n-tiles x RT row-tiles, B from transposed bf16 weights [N][K]
__device__ __forceinline__ void mm_step(const ushort* __restrict__ wT, int K, int ks, int l15, int kg,
                                        const short8 a[RT], f32x4 acc[RT][8]) {
#pragma unroll
  for (int nt = 0; nt < 8; ++nt) {
    short8 b = *reinterpret_cast<const short8*>(wT + (nt * 16 + l15) * K + ks * 32 + kg);
#pragma unroll
    for (int rt = 0; rt < RT; ++rt)
      acc[rt][nt] = __builtin_amdgcn_mfma_f32_16x16x32_bf16(a[rt], b, acc[rt][nt], 0, 0, 0);
  }
}

// Fused edge-MLP + node-MLP. Each WAVE independently owns 32 edges.
// NO out_x atomics: msg is written bf16 to ws; reduce_k does the scatter-mean.
__global__ __launch_bounds__(256, 4) void fused_k(
    const int* __restrict__ ei, const float* __restrict__ edge_attr,
    const ushort* __restrict__ wt,
    const float* __restrict__ eb1, const float* __restrict__ eb2,
    const float* __restrict__ nb1, const float* __restrict__ nb2,
    const ushort* __restrict__ xb,
    ushort* __restrict__ msg, float* __restrict__ out_e)
{
  __shared__ ushort hbuf[4][RT * 16][136];
  const int lane = threadIdx.x & 63;
  const int widx = threadIdx.x >> 6;
  const int wtile = blockIdx.x * 4 + widx;
  const int base = wtile * (RT * 16);
  if (base >= NE) return;
  const int l15 = lane & 15;
  const int g = lane >> 4;
  const int kg = g * 8;
  ushort (*h)[136] = hbuf[widx];

  const ushort* ew1T = wt;
  const ushort* ew2T = wt + 49152;
  const ushort* nw1T = wt + 65536;
  const ushort* nw2T = wt + 98304;

  int rowA[RT], colA[RT], eA[RT];
#pragma unroll
  for (int rt = 0; rt < RT; ++rt) {
    eA[rt] = base + rt * 16 + l15;
    rowA[rt] = ei[eA[rt]];
    colA[rt] = ei[NE + eA[rt]];
  }

  const f32x4 zero4 = {0.f, 0.f, 0.f, 0.f};
  f32x4 acc[RT][8];

  // ================= GEMM1: h1 = relu([x[row]|x[col]|edge_attr] @ ew1 + eb1) =================
#pragma unroll
  for (int rt = 0; rt < RT; ++rt)
#pragma unroll
    for (int nt = 0; nt < 8; ++nt) acc[rt][nt] = zero4;

#pragma unroll
  for (int ks = 0; ks < 4; ++ks) {               // k 0..127: x[row]
    short8 a[RT];
#pragma unroll
    for (int rt = 0; rt < RT; ++rt)
      a[rt] = *reinterpret_cast<const short8*>(xb + rowA[rt] * CH + ks * 32 + kg);
    mm_step(ew1T, 384, ks, l15, kg, a, acc);
  }
#pragma unroll
  for (int ks = 4; ks < 8; ++ks) {               // k 128..255: x[col]
    short8 a[RT];
#pragma unroll
    for (int rt = 0; rt < RT; ++rt)
      a[rt] = *reinterpret_cast<const short8*>(xb + colA[rt] * CH + (ks - 4) * 32 + kg);
    mm_step(ew1T, 384, ks, l15, kg, a, acc);
  }
#pragma unroll
  for (int ks = 8; ks < 12; ++ks) {              // k 256..383: edge_attr (fp32 -> bf16 on the fly)
    short8 a[RT];
#pragma unroll
    for (int rt = 0; rt < RT; ++rt) {
      const float* p = edge_attr + (size_t)eA[rt] * CH + (ks - 8) * 32 + kg;
      float4 f0 = *reinterpret_cast<const float4*>(p);
      float4 f1 = *reinterpret_cast<const float4*>(p + 4);
      short8 t;
      t[0] = (short)f2bf(f0.x); t[1] = (short)f2bf(f0.y); t[2] = (short)f2bf(f0.z); t[3] = (short)f2bf(f0.w);
      t[4] = (short)f2bf(f1.x); t[5] = (short)f2bf(f1.y); t[6] = (short)f2bf(f1.z); t[7] = (short)f2bf(f1.w);
      a[rt] = t;
    }
    mm_step(ew1T, 384, ks, l15, kg, a, acc);
  }
  // epilogue 1 -> LDS (C/D layout: row=(l>>4)*4+reg, col=l&15)
#pragma unroll
  for (int nt = 0; nt < 8; ++nt) {
    float bb = eb1[nt * 16 + l15];
#pragma unroll
    for (int rt = 0; rt < RT; ++rt)
#pragma unroll
      for (int r = 0; r < 4; ++r) {
        float v = fmaxf(acc[rt][nt][r] + bb, 0.f);
        h[rt * 16 + g * 4 + r][nt * 16 + l15] = f2bf(v);
      }
  }

  // ================= GEMM2: e_out = h1 @ ew2 + eb2 =================
#pragma unroll
  for (int rt = 0; rt < RT; ++rt)
#pragma unroll
    for (int nt = 0; nt < 8; ++nt) acc[rt][nt] = zero4;
#pragma unroll
  for (int ks = 0; ks < 4; ++ks) {
    short8 a[RT];
#pragma unroll
    for (int rt = 0; rt < RT; ++rt)
      a[rt] = *reinterpret_cast<const short8*>(&h[rt * 16 + l15][ks * 32 + kg]);
    mm_step(ew2T, 128, ks, l15, kg, a, acc);
  }
  // epilogue 2: store new_edge_attr (fp32) + bf16 copy back to LDS for GEMM3
#pragma unroll
  for (int nt = 0; nt < 8; ++nt) {
    float bb = eb2[nt * 16 + l15];
#pragma unroll
    for (int rt = 0; rt < RT; ++rt)
#pragma unroll
      for (int r = 0; r < 4; ++r) {
        float v = acc[rt][nt][r] + bb;
        int erow = base + rt * 16 + g * 4 + r;
        out_e[(size_t)erow * CH + nt * 16 + l15] = v;
        h[rt * 16 + g * 4 + r][nt * 16 + l15] = f2bf(v);
      }
  }

  // ================= GEMM3: h2 = relu([x[col]|e_out] @ nw1 + nb1) =================
#pragma unroll
  for (int rt = 0; rt < RT; ++rt)
#pragma unroll
    for (int nt = 0; nt < 8; ++nt) acc[rt][nt] = zero4;
#pragma unroll
  for (int ks = 0; ks < 4; ++ks) {               // k 0..127: x[col]
    short8 a[RT];
#pragma unroll
    for (int rt = 0; rt < RT; ++rt)
      a[rt] = *reinterpret_cast<const short8*>(xb + colA[rt] * CH + ks * 32 + kg);
    mm_step(nw1T, 256, ks, l15, kg, a, acc);
  }
#pragma unroll
  for (int ks = 4; ks < 8; ++ks) {               // k 128..255: e_out from LDS
    short8 a[RT];
#pragma unroll
    for (int rt = 0; rt < RT; ++rt)
      a[rt] = *reinterpret_cast<const short8*>(&h[rt * 16 + l15][(ks - 4) * 32 + kg]);
    mm_step(nw1T, 256, ks, l15, kg, a, acc);
  }
  // epilogue 3 -> LDS
#pragma unroll
  for (int nt = 0; nt < 8; ++nt) {
    float bb = nb1[nt * 16 + l15];
#pragma unroll
    for (int rt = 0; rt < RT; ++rt)
#pragma unroll
      for (int r = 0; r < 4; ++r) {
        float v = fmaxf(acc[rt][nt][r] + bb, 0.f);
        h[rt * 16 + g * 4 + r][nt * 16 + l15] = f2bf(v);
      }
  }

  // ================= GEMM4: msg = h2 @ nw2 + nb2 -> bf16 to ws =================
#pragma unroll
  for (int rt = 0; rt < RT; ++rt)
#pragma unroll
    for (int nt = 0; nt < 8; ++nt) acc[rt][nt] = zero4;
#pragma unroll
  for (int ks = 0; ks < 4; ++ks) {
    short8 a[RT];
#pragma unroll
    for (int rt = 0; rt < RT; ++rt)
      a[rt] = *reinterpret_cast<const short8*>(&h[rt * 16 + l15][ks * 32 + kg]);
    mm_step(nw2T, 128, ks, l15, kg, a, acc);
  }
#pragma unroll
  for (int nt = 0; nt < 8; ++nt) {
    float bb = nb2[nt * 16 + l15];
#pragma unroll
    for (int rt = 0; rt < RT; ++rt)
#pragma unroll
      for (int r = 0; r < 4; ++r) {
        int erow = base + rt * 16 + g * 4 + r;
        msg[(size_t)erow * CH + nt * 16 + l15] = f2bf(acc[rt][nt][r] + bb);
      }
  }
}

// scatter-mean via CSR: one wave per node, fp32 accumulate, no atomics.
__global__ __launch_bounds__(256) void reduce_k(const ushort* __restrict__ msg,
    const unsigned* __restrict__ cnt, const unsigned* __restrict__ start,
    const unsigned* __restrict__ eidx, float* __restrict__ out_x) {
  int w = blockIdx.x * 4 + (threadIdx.x >> 6);
  if (w >= NN) return;
  int lane = threadIdx.x & 63;
  unsigned deg = cnt[w], s = start[w];
  float a0 = 0.f, a1 = 0.f;
#pragma unroll 4
  for (unsigned j = 0; j < deg; ++j) {
    unsigned e = eidx[s + j];
    uint32_t pk = *reinterpret_cast<const uint32_t*>(msg + (size_t)e * CH + lane * 2);
    a0 += bf2f(pk & 0xffffu);
    a1 += bf2f(pk >> 16);
  }
  float inv = 1.0f / fmaxf((float)deg, 1.0f);
  float2 o; o.x = a0 * inv; o.y = a1 * inv;
  *reinterpret_cast<float2*>(out_x + (size_t)w * CH + lane * 2) = o;
}

extern "C" void kernel_launch(void* const* d_in, const int* in_sizes, int n_in,
                              void* d_out, int out_size, void* d_ws, size_t ws_size,
                              hipStream_t stream) {
  const float* x   = (const float*)d_in[0];
  const int*   ei  = (const int*)d_in[1];
  const float* ea  = (const float*)d_in[2];
  const float* ew1 = (const float*)d_in[3];
  const float* eb1 = (const float*)d_in[4];
  const float* ew2 = (const float*)d_in[5];
  const float* eb2 = (const float*)d_in[6];
  const float* nw1 = (const float*)d_in[7];
  const float* nb1 = (const float*)d_in[8];
  const float* nw2 = (const float*)d_in[9];
  const float* nb2 = (const float*)d_in[10];

  float* out_x = (float*)d_out;                          // [NN][CH]
  float* out_e = (float*)d_out + (size_t)NN * CH;        // [NE][CH]

  // ws layout (all offsets 64B-aligned), ~170 MB total:
  // msg bf16 [NE][CH] @0 | wt @153.6M | xb @153.83M | cnt | start | cursor | eidx
  char* wsb = (char*)d_ws;
  ushort*   msg    = (ushort*)wsb;                                   // 153,600,000 B
  ushort*   wt     = (ushort*)(wsb + 153600000);                     //     229,376 B
  ushort*   xb     = (ushort*)(wsb + 153829376);                     //  12,800,000 B
  unsigned* cnt    = (unsigned*)(wsb + 166629376);                   //     200,000 B
  unsigned* start  = (unsigned*)(wsb + 166829376);                   //     200,000 B
  unsigned* cursor = (unsigned*)(wsb + 167029376);                   //     200,000 B
  unsigned* eidx   = (unsigned*)(wsb + 167229376);                   //   2,400,000 B -> end 169,629,376

  hipMemsetAsync(cnt, 0, (size_t)NN * sizeof(unsigned), stream);
  hipMemsetAsync(cursor, 0, (size_t)NN * sizeof(unsigned), stream);

  prep_weights_k<<<448, 256, 0, stream>>>(ew1, ew2, nw1, nw2, wt);
  convert_x_k<<<(NN * CH / 4 + 255) / 256, 256, 0, stream>>>(x, xb);
  histogram_k<<<(NE + 255) / 256, 256, 0, stream>>>(ei, cnt);
  scan_k<<<1, 1024, 0, stream>>>(cnt, start);
  scatter_k<<<(NE + 255) / 256, 256, 0, stream>>>(ei, start, cursor, eidx);

  int wave_tiles = NE / (RT * 16);                       // 18750
  fused_k<<<(wave_tiles + 3) / 4, 256, 0, stream>>>(ei, ea, wt, eb1, eb2, nb1, nb2, xb, msg, out_e);

  reduce_k<<<(NN + 3) / 4, 256, 0, stream>>>(msg, cnt, start, eidx, out_x);
}

// Round 4
// 661.726 us; speedup vs baseline: 1.3572x; 1.3572x over previous
//
#include <hip/hip_runtime.h>
#include <stdint.h>

#define NN 50000
#define NE 600000
#define CH 128
#define RT 4                      // row-tiles (of 16 edges) per wave -> 64 edges/wave

typedef __attribute__((ext_vector_type(8))) short short8;   // 8 bf16
typedef __attribute__((ext_vector_type(4))) float f32x4;

__device__ __forceinline__ ushort f2bf(float f) {
  union { float f; uint32_t u; } v; v.f = f;
  uint32_t u = v.u;
  return (ushort)((u + 0x7FFFu + ((u >> 16) & 1u)) >> 16);  // RNE, inputs finite
}
__device__ __forceinline__ float bf2f(uint32_t u16) {
  union { uint32_t u; float f; } t; t.u = u16 << 16; return t.f;
}

// ---- prep: pack weights into exact MFMA-fragment order, bf16 ----
// wB layout (ushort): per GEMM region, element ((ks*8+nt)*512 + lane*8 + i)
//   = W[k = ks*32 + (lane>>4)*8 + i][n = nt*16 + (lane&15)]  (all W are [K][128])
// regions: G1 ew1 @0 (12 ks), G2 ew2 @49152 (4 ks), G3 nw1 @65536 (8 ks), G4 nw2 @98304 (4 ks)
__global__ void prep_frag_k(const float* __restrict__ ew1, const float* __restrict__ ew2,
                            const float* __restrict__ nw1, const float* __restrict__ nw2,
                            ushort* __restrict__ wB) {
  int idx = blockIdx.x * 256 + threadIdx.x;
  if (idx >= 114688) return;
  const float* src; int local;
  if (idx < 49152)      { src = ew1; local = idx; }
  else if (idx < 65536) { src = ew2; local = idx - 49152; }
  else if (idx < 98304) { src = nw1; local = idx - 65536; }
  else                  { src = nw2; local = idx - 98304; }
  int ks   = local >> 12;
  int rem  = local & 4095;
  int nt   = rem >> 9;
  int t    = rem & 511;
  int lane = t >> 3, i = t & 7;
  int k = ks * 32 + (lane >> 4) * 8 + i;
  int n = nt * 16 + (lane & 15);
  wB[idx] = f2bf(src[k * 128 + n]);
}

__global__ void convert_x_k(const float* __restrict__ x, ushort* __restrict__ xb) {
  int i = blockIdx.x * 256 + threadIdx.x;          // over NN*CH/4 float4s
  if (i >= NN * CH / 4) return;
  const float4 f = reinterpret_cast<const float4*>(x)[i];
  ushort4 r;
  r.x = f2bf(f.x); r.y = f2bf(f.y); r.z = f2bf(f.z); r.w = f2bf(f.w);
  reinterpret_cast<ushort4*>(xb)[i] = r;
}

__global__ void histogram_k(const int* __restrict__ ei, unsigned* __restrict__ cnt) {
  int e = blockIdx.x * 256 + threadIdx.x;
  if (e < NE) atomicAdd(&cnt[ei[e]], 1u);
}

// single-block exclusive prefix sum over cnt[NN] -> start[NN]
__global__ void scan_k(const unsigned* __restrict__ cnt, unsigned* __restrict__ start) {
  __shared__ unsigned s[1024];
  const int CHUNK = (NN + 1023) / 1024;            // 49
  int t = threadIdx.x;
  int lo = t * CHUNK, hi = lo + CHUNK < NN ? lo + CHUNK : NN;
  unsigned sum = 0;
  for (int i = lo; i < hi; ++i) sum += cnt[i];
  s[t] = sum;
  __syncthreads();
  for (int off = 1; off < 1024; off <<= 1) {       // Hillis-Steele inclusive
    unsigned v = (t >= off) ? s[t - off] : 0u;
    __syncthreads();
    s[t] += v;
    __syncthreads();
  }
  unsigned run = t ? s[t - 1] : 0u;
  for (int i = lo; i < hi; ++i) { start[i] = run; run += cnt[i]; }
}

// build per-node edge lists (CSR)
__global__ void scatter_k(const int* __restrict__ ei, const unsigned* __restrict__ start,
                          unsigned* __restrict__ cursor, unsigned* __restrict__ eidx) {
  int e = blockIdx.x * 256 + threadIdx.x;
  if (e < NE) {
    int r = ei[e];
    unsigned pos = start[r] + atomicAdd(&cursor[r], 1u);
    eidx[pos] = e;
  }
}

// one MFMA k-step: B loads are COALESCED lane-linear 16B from fragment-packed wB
__device__ __forceinline__ void mm_step(const ushort* __restrict__ wf, int lane,
                                        const short8 a[RT], f32x4 acc[RT][8]) {
#pragma unroll
  for (int nt = 0; nt < 8; ++nt) {
    short8 b = *reinterpret_cast<const short8*>(wf + nt * 512 + lane * 8);
#pragma unroll
    for (int rt = 0; rt < RT; ++rt)
      acc[rt][nt] = __builtin_amdgcn_mfma_f32_16x16x32_bf16(a[rt], b, acc[rt][nt], 0, 0, 0);
  }
}

// Fused edge-MLP + node-MLP. Each WAVE independently owns 64 edges. No barriers.
// msg written bf16 (coalesced via LDS); out_e scalar fp32 (exact).
__global__ __launch_bounds__(256, 2) void fused_k(
    const int* __restrict__ ei, const float* __restrict__ edge_attr,
    const ushort* __restrict__ wB,
    const float* __restrict__ eb1, const float* __restrict__ eb2,
    const float* __restrict__ nb1, const float* __restrict__ nb2,
    const ushort* __restrict__ xb,
    ushort* __restrict__ msg, float* __restrict__ out_e)
{
  __shared__ ushort hbuf[4][RT * 16][136];
  const int lane = threadIdx.x & 63;
  const int widx = threadIdx.x >> 6;
  const int wtile = blockIdx.x * 4 + widx;
  const int base = wtile * (RT * 16);
  if (base >= NE) return;
  const int l15 = lane & 15;
  const int g = lane >> 4;
  const int kg = g * 8;
  ushort (*h)[136] = hbuf[widx];

  const ushort* g1 = wB;            // 12 ks
  const ushort* g2 = wB + 49152;    // 4 ks
  const ushort* g3 = wB + 65536;    // 8 ks
  const ushort* g4 = wB + 98304;    // 4 ks

  int rowA[RT], colA[RT], eA[RT];
#pragma unroll
  for (int rt = 0; rt < RT; ++rt) {
    eA[rt] = base + rt * 16 + l15;
    rowA[rt] = ei[eA[rt]];
    colA[rt] = ei[NE + eA[rt]];
  }

  const f32x4 zero4 = {0.f, 0.f, 0.f, 0.f};
  f32x4 acc[RT][8];

  // ================= GEMM1: h1 = relu([x[row]|x[col]|edge_attr] @ ew1 + eb1) =================
#pragma unroll
  for (int rt = 0; rt < RT; ++rt)
#pragma unroll
    for (int nt = 0; nt < 8; ++nt) acc[rt][nt] = zero4;

#pragma unroll
  for (int ks = 0; ks < 4; ++ks) {               // k 0..127: x[row]
    short8 a[RT];
#pragma unroll
    for (int rt = 0; rt < RT; ++rt)
      a[rt] = *reinterpret_cast<const short8*>(xb + rowA[rt] * CH + ks * 32 + kg);
    mm_step(g1 + ks * 4096, lane, a, acc);
  }
#pragma unroll
  for (int ks = 4; ks < 8; ++ks) {               // k 128..255: x[col]
    short8 a[RT];
#pragma unroll
    for (int rt = 0; rt < RT; ++rt)
      a[rt] = *reinterpret_cast<const short8*>(xb + colA[rt] * CH + (ks - 4) * 32 + kg);
    mm_step(g1 + ks * 4096, lane, a, acc);
  }
#pragma unroll
  for (int ks = 8; ks < 12; ++ks) {              // k 256..383: edge_attr (fp32 -> bf16 on the fly)
    short8 a[RT];
#pragma unroll
    for (int rt = 0; rt < RT; ++rt) {
      const float* p = edge_attr + (size_t)eA[rt] * CH + (ks - 8) * 32 + kg;
      float4 f0 = *reinterpret_cast<const float4*>(p);
      float4 f1 = *reinterpret_cast<const float4*>(p + 4);
      short8 t;
      t[0] = (short)f2bf(f0.x); t[1] = (short)f2bf(f0.y); t[2] = (short)f2bf(f0.z); t[3] = (short)f2bf(f0.w);
      t[4] = (short)f2bf(f1.x); t[5] = (short)f2bf(f1.y); t[6] = (short)f2bf(f1.z); t[7] = (short)f2bf(f1.w);
      a[rt] = t;
    }
    mm_step(g1 + ks * 4096, lane, a, acc);
  }
  // epilogue 1 -> LDS (C/D layout: row=(l>>4)*4+reg, col=l&15)
#pragma unroll
  for (int nt = 0; nt < 8; ++nt) {
    float bb = eb1[nt * 16 + l15];
#pragma unroll
    for (int rt = 0; rt < RT; ++rt)
#pragma unroll
      for (int r = 0; r < 4; ++r) {
        float v = fmaxf(acc[rt][nt][r] + bb, 0.f);
        h[rt * 16 + g * 4 + r][nt * 16 + l15] = f2bf(v);
      }
  }

  // ================= GEMM2: e_out = h1 @ ew2 + eb2 =================
#pragma unroll
  for (int rt = 0; rt < RT; ++rt)
#pragma unroll
    for (int nt = 0; nt < 8; ++nt) acc[rt][nt] = zero4;
#pragma unroll
  for (int ks = 0; ks < 4; ++ks) {
    short8 a[RT];
#pragma unroll
    for (int rt = 0; rt < RT; ++rt)
      a[rt] = *reinterpret_cast<const short8*>(&h[rt * 16 + l15][ks * 32 + kg]);
    mm_step(g2 + ks * 4096, lane, a, acc);
  }
  // epilogue 2: store new_edge_attr (fp32, exact) + bf16 copy back to LDS for GEMM3
#pragma unroll
  for (int nt = 0; nt < 8; ++nt) {
    float bb = eb2[nt * 16 + l15];
#pragma unroll
    for (int rt = 0; rt < RT; ++rt)
#pragma unroll
      for (int r = 0; r < 4; ++r) {
        float v = acc[rt][nt][r] + bb;
        int erow = base + rt * 16 + g * 4 + r;
        out_e[(size_t)erow * CH + nt * 16 + l15] = v;
        h[rt * 16 + g * 4 + r][nt * 16 + l15] = f2bf(v);
      }
  }

  // ================= GEMM3: h2 = relu([x[col]|e_out] @ nw1 + nb1) =================
#pragma unroll
  for (int rt = 0; rt < RT; ++rt)
#pragma unroll
    for (int nt = 0; nt < 8; ++nt) acc[rt][nt] = zero4;
#pragma unroll
  for (int ks = 0; ks < 4; ++ks) {               // k 0..127: x[col]
    short8 a[RT];
#pragma unroll
    for (int rt = 0; rt < RT; ++rt)
      a[rt] = *reinterpret_cast<const short8*>(xb + colA[rt] * CH + ks * 32 + kg);
    mm_step(g3 + ks * 4096, lane, a, acc);
  }
#pragma unroll
  for (int ks = 4; ks < 8; ++ks) {               // k 128..255: e_out from LDS
    short8 a[RT];
#pragma unroll
    for (int rt = 0; rt < RT; ++rt)
      a[rt] = *reinterpret_cast<const short8*>(&h[rt * 16 + l15][(ks - 4) * 32 + kg]);
    mm_step(g3 + ks * 4096, lane, a, acc);
  }
  // epilogue 3 -> LDS
#pragma unroll
  for (int nt = 0; nt < 8; ++nt) {
    float bb = nb1[nt * 16 + l15];
#pragma unroll
    for (int rt = 0; rt < RT; ++rt)
#pragma unroll
      for (int r = 0; r < 4; ++r) {
        float v = fmaxf(acc[rt][nt][r] + bb, 0.f);
        h[rt * 16 + g * 4 + r][nt * 16 + l15] = f2bf(v);
      }
  }

  // ================= GEMM4: msg = h2 @ nw2 + nb2 -> LDS -> coalesced bf16 stores =================
#pragma unroll
  for (int rt = 0; rt < RT; ++rt)
#pragma unroll
    for (int nt = 0; nt < 8; ++nt) acc[rt][nt] = zero4;
#pragma unroll
  for (int ks = 0; ks < 4; ++ks) {
    short8 a[RT];
#pragma unroll
    for (int rt = 0; rt < RT; ++rt)
      a[rt] = *reinterpret_cast<const short8*>(&h[rt * 16 + l15][ks * 32 + kg]);
    mm_step(g4 + ks * 4096, lane, a, acc);
  }
#pragma unroll
  for (int nt = 0; nt < 8; ++nt) {
    float bb = nb2[nt * 16 + l15];
#pragma unroll
    for (int rt = 0; rt < RT; ++rt)
#pragma unroll
      for (int r = 0; r < 4; ++r)
        h[rt * 16 + g * 4 + r][nt * 16 + l15] = f2bf(acc[rt][nt][r] + bb);
  }
  // coalesced msg stores: 16 iters x (1 ds_read_b128 + 1 global_store_dwordx4)
#pragma unroll
  for (int it = 0; it < 16; ++it) {
    int row = it * 4 + (lane >> 4);
    int col = l15 * 8;
    short8 v = *reinterpret_cast<const short8*>(&h[row][col]);
    *reinterpret_cast<short8*>(msg + (size_t)(base + row) * CH + col) = v;
  }
}

// scatter-mean via CSR: one wave per node, fp32 accumulate, no atomics.
__global__ __launch_bounds__(256) void reduce_k(const ushort* __restrict__ msg,
    const unsigned* __restrict__ cnt, const unsigned* __restrict__ start,
    const unsigned* __restrict__ eidx, float* __restrict__ out_x) {
  int w = blockIdx.x * 4 + (threadIdx.x >> 6);
  if (w >= NN) return;
  int lane = threadIdx.x & 63;
  unsigned deg = cnt[w], s = start[w];
  float a0 = 0.f, a1 = 0.f;
#pragma unroll 4
  for (unsigned j = 0; j < deg; ++j) {
    unsigned e = eidx[s + j];
    uint32_t pk = *reinterpret_cast<const uint32_t*>(msg + (size_t)e * CH + lane * 2);
    a0 += bf2f(pk & 0xffffu);
    a1 += bf2f(pk >> 16);
  }
  float inv = 1.0f / fmaxf((float)deg, 1.0f);
  float2 o; o.x = a0 * inv; o.y = a1 * inv;
  *reinterpret_cast<float2*>(out_x + (size_t)w * CH + lane * 2) = o;
}

extern "C" void kernel_launch(void* const* d_in, const int* in_sizes, int n_in,
                              void* d_out, int out_size, void* d_ws, size_t ws_size,
                              hipStream_t stream) {
  const float* x   = (const float*)d_in[0];
  const int*   ei  = (const int*)d_in[1];
  const float* ea  = (const float*)d_in[2];
  const float* ew1 = (const float*)d_in[3];
  const float* eb1 = (const float*)d_in[4];
  const float* ew2 = (const float*)d_in[5];
  const float* eb2 = (const float*)d_in[6];
  const float* nw1 = (const float*)d_in[7];
  const float* nb1 = (const float*)d_in[8];
  const float* nw2 = (const float*)d_in[9];
  const float* nb2 = (const float*)d_in[10];

  float* out_x = (float*)d_out;                          // [NN][CH]
  float* out_e = (float*)d_out + (size_t)NN * CH;        // [NE][CH]

  // ws layout: msg bf16 [NE][CH] @0 | wB @153.6M | xb | cnt | start | cursor | eidx
  char* wsb = (char*)d_ws;
  ushort*   msg    = (ushort*)wsb;                                   // 153,600,000 B
  ushort*   wB     = (ushort*)(wsb + 153600000);                     //     229,376 B
  ushort*   xb     = (ushort*)(wsb + 153829376);                     //  12,800,000 B
  unsigned* cnt    = (unsigned*)(wsb + 166629376);                   //     200,000 B
  unsigned* start  = (unsigned*)(wsb + 166829376);                   //     200,000 B
  unsigned* cursor = (unsigned*)(wsb + 167029376);                   //     200,000 B
  unsigned* eidx   = (unsigned*)(wsb + 167229376);                   //   2,400,000 B

  hipMemsetAsync(cnt, 0, (size_t)NN * sizeof(unsigned), stream);
  hipMemsetAsync(cursor, 0, (size_t)NN * sizeof(unsigned), stream);

  prep_frag_k<<<448, 256, 0, stream>>>(ew1, ew2, nw1, nw2, wB);
  convert_x_k<<<(NN * CH / 4 + 255) / 256, 256, 0, stream>>>(x, xb);
  histogram_k<<<(NE + 255) / 256, 256, 0, stream>>>(ei, cnt);
  scan_k<<<1, 1024, 0, stream>>>(cnt, start);
  scatter_k<<<(NE + 255) / 256, 256, 0, stream>>>(ei, start, cursor, eidx);

  int wave_tiles = NE / (RT * 16);                       // 9375
  fused_k<<<(wave_tiles + 3) / 4, 256, 0, stream>>>(ei, ea, wB, eb1, eb2, nb1, nb2, xb, msg, out_e);

  reduce_k<<<(NN + 3) / 4, 256, 0, stream>>>(msg, cnt, start, eidx, out_x);
}

// Round 5
// 642.156 us; speedup vs baseline: 1.3986x; 1.0305x over previous
//
#include <hip/hip_runtime.h>
#include <stdint.h>

#define NN 50000
#define NE 600000
#define CH 128
#define RT 3                      // row-tiles (of 16 edges) per wave -> 48 edges/wave

typedef __attribute__((ext_vector_type(8))) short short8;   // 8 bf16
typedef __attribute__((ext_vector_type(4))) float f32x4;
typedef __attribute__((ext_vector_type(4))) uint32_t u32x4;

__device__ __forceinline__ ushort f2bf(float f) {
  union { float f; uint32_t u; } v; v.f = f;
  uint32_t u = v.u;
  return (ushort)((u + 0x7FFFu + ((u >> 16) & 1u)) >> 16);  // RNE, inputs finite
}
__device__ __forceinline__ float bf2f(uint32_t u16) {
  union { uint32_t u; float f; } t; t.u = u16 << 16; return t.f;
}
// pack two f32 -> two bf16 (RNE) in ONE VALU op
__device__ __forceinline__ uint32_t cvtpk_bf16(float a, float b) {
  uint32_t r;
  asm("v_cvt_pk_bf16_f32 %0, %1, %2" : "=v"(r) : "v"(a), "v"(b));
  return r;
}

// ---- prep: pack weights into exact MFMA-fragment order, bf16 ----
// wB layout (ushort): per GEMM region, element ((ks*8+nt)*512 + lane*8 + i)
//   = W[k = ks*32 + (lane>>4)*8 + i][n = nt*16 + (lane&15)]  (all W are [K][128])
// regions: G1 ew1 @0 (12 ks), G2 ew2 @49152 (4 ks), G3 nw1 @65536 (8 ks), G4 nw2 @98304 (4 ks)
__global__ void prep_frag_k(const float* __restrict__ ew1, const float* __restrict__ ew2,
                            const float* __restrict__ nw1, const float* __restrict__ nw2,
                            ushort* __restrict__ wB) {
  int idx = blockIdx.x * 256 + threadIdx.x;
  if (idx >= 114688) return;
  const float* src; int local;
  if (idx < 49152)      { src = ew1; local = idx; }
  else if (idx < 65536) { src = ew2; local = idx - 49152; }
  else if (idx < 98304) { src = nw1; local = idx - 65536; }
  else                  { src = nw2; local = idx - 98304; }
  int ks   = local >> 12;
  int rem  = local & 4095;
  int nt   = rem >> 9;
  int t    = rem & 511;
  int lane = t >> 3, i = t & 7;
  int k = ks * 32 + (lane >> 4) * 8 + i;
  int n = nt * 16 + (lane & 15);
  wB[idx] = f2bf(src[k * 128 + n]);
}

__global__ void convert_x_k(const float* __restrict__ x, ushort* __restrict__ xb) {
  int i = blockIdx.x * 256 + threadIdx.x;          // over NN*CH/4 float4s
  if (i >= NN * CH / 4) return;
  const float4 f = reinterpret_cast<const float4*>(x)[i];
  ushort4 r;
  r.x = f2bf(f.x); r.y = f2bf(f.y); r.z = f2bf(f.z); r.w = f2bf(f.w);
  reinterpret_cast<ushort4*>(xb)[i] = r;
}

__global__ void histogram_k(const int* __restrict__ ei, unsigned* __restrict__ cnt) {
  int e = blockIdx.x * 256 + threadIdx.x;
  if (e < NE) atomicAdd(&cnt[ei[e]], 1u);
}

// single-block exclusive prefix sum over cnt[NN] -> start[NN]
__global__ void scan_k(const unsigned* __restrict__ cnt, unsigned* __restrict__ start) {
  __shared__ unsigned s[1024];
  const int CHUNK = (NN + 1023) / 1024;            // 49
  int t = threadIdx.x;
  int lo = t * CHUNK, hi = lo + CHUNK < NN ? lo + CHUNK : NN;
  unsigned sum = 0;
  for (int i = lo; i < hi; ++i) sum += cnt[i];
  s[t] = sum;
  __syncthreads();
  for (int off = 1; off < 1024; off <<= 1) {       // Hillis-Steele inclusive
    unsigned v = (t >= off) ? s[t - off] : 0u;
    __syncthreads();
    s[t] += v;
    __syncthreads();
  }
  unsigned run = t ? s[t - 1] : 0u;
  for (int i = lo; i < hi; ++i) { start[i] = run; run += cnt[i]; }
}

// build per-node edge lists (CSR)
__global__ void scatter_k(const int* __restrict__ ei, const unsigned* __restrict__ start,
                          unsigned* __restrict__ cursor, unsigned* __restrict__ eidx) {
  int e = blockIdx.x * 256 + threadIdx.x;
  if (e < NE) {
    int r = ei[e];
    unsigned pos = start[r] + atomicAdd(&cursor[r], 1u);
    eidx[pos] = e;
  }
}

// one MFMA k-step: B loads are COALESCED lane-linear 16B from fragment-packed wB
__device__ __forceinline__ void mm_step(const ushort* __restrict__ wf, int lane,
                                        const short8 a[RT], f32x4 acc[RT][8]) {
#pragma unroll
  for (int nt = 0; nt < 8; ++nt) {
    short8 b = *reinterpret_cast<const short8*>(wf + nt * 512 + lane * 8);
#pragma unroll
    for (int rt = 0; rt < RT; ++rt)
      acc[rt][nt] = __builtin_amdgcn_mfma_f32_16x16x32_bf16(a[rt], b, acc[rt][nt], 0, 0, 0);
  }
}

// Fused edge-MLP + node-MLP. Each WAVE independently owns 48 edges. No barriers.
// LDS 52.2 KB/block -> 3 blocks/CU (12 waves/CU, 3/SIMD) vs 2 at RT=4.
__global__ __launch_bounds__(256, 3) void fused_k(
    const int* __restrict__ ei, const float* __restrict__ edge_attr,
    const ushort* __restrict__ wB,
    const float* __restrict__ eb1, const float* __restrict__ eb2,
    const float* __restrict__ nb1, const float* __restrict__ nb2,
    const ushort* __restrict__ xb,
    ushort* __restrict__ msg, float* __restrict__ out_e)
{
  __shared__ ushort hbuf[4][RT * 16][136];
  const int lane = threadIdx.x & 63;
  const int widx = threadIdx.x >> 6;
  const int wtile = blockIdx.x * 4 + widx;
  const int base = wtile * (RT * 16);
  if (base >= NE) return;
  const int l15 = lane & 15;
  const int g = lane >> 4;
  const int kg = g * 8;
  ushort (*h)[136] = hbuf[widx];

  const ushort* g1 = wB;            // 12 ks
  const ushort* g2 = wB + 49152;    // 4 ks
  const ushort* g3 = wB + 65536;    // 8 ks
  const ushort* g4 = wB + 98304;    // 4 ks

  int rowA[RT], colA[RT], eA[RT];
#pragma unroll
  for (int rt = 0; rt < RT; ++rt) {
    eA[rt] = base + rt * 16 + l15;
    rowA[rt] = ei[eA[rt]];
    colA[rt] = ei[NE + eA[rt]];
  }

  const f32x4 zero4 = {0.f, 0.f, 0.f, 0.f};
  f32x4 acc[RT][8];

  // ================= GEMM1: h1 = relu([x[row]|x[col]|edge_attr] @ ew1 + eb1) =================
#pragma unroll
  for (int rt = 0; rt < RT; ++rt)
#pragma unroll
    for (int nt = 0; nt < 8; ++nt) acc[rt][nt] = zero4;

#pragma unroll
  for (int ks = 0; ks < 4; ++ks) {               // k 0..127: x[row]
    short8 a[RT];
#pragma unroll
    for (int rt = 0; rt < RT; ++rt)
      a[rt] = *reinterpret_cast<const short8*>(xb + rowA[rt] * CH + ks * 32 + kg);
    mm_step(g1 + ks * 4096, lane, a, acc);
  }
#pragma unroll
  for (int ks = 4; ks < 8; ++ks) {               // k 128..255: x[col]
    short8 a[RT];
#pragma unroll
    for (int rt = 0; rt < RT; ++rt)
      a[rt] = *reinterpret_cast<const short8*>(xb + colA[rt] * CH + (ks - 4) * 32 + kg);
    mm_step(g1 + ks * 4096, lane, a, acc);
  }
#pragma unroll
  for (int ks = 8; ks < 12; ++ks) {              // k 256..383: edge_attr (fp32 -> bf16 via cvt_pk)
    short8 a[RT];
#pragma unroll
    for (int rt = 0; rt < RT; ++rt) {
      const float* p = edge_attr + (size_t)eA[rt] * CH + (ks - 8) * 32 + kg;
      float4 f0 = *reinterpret_cast<const float4*>(p);
      float4 f1 = *reinterpret_cast<const float4*>(p + 4);
      union { u32x4 u; short8 s; } cv;
      cv.u = (u32x4){ cvtpk_bf16(f0.x, f0.y), cvtpk_bf16(f0.z, f0.w),
                      cvtpk_bf16(f1.x, f1.y), cvtpk_bf16(f1.z, f1.w) };
      a[rt] = cv.s;
    }
    mm_step(g1 + ks * 4096, lane, a, acc);
  }
  // epilogue 1 -> LDS (C/D layout: row=(l>>4)*4+reg, col=l&15)
#pragma unroll
  for (int nt = 0; nt < 8; ++nt) {
    float bb = eb1[nt * 16 + l15];
#pragma unroll
    for (int rt = 0; rt < RT; ++rt)
#pragma unroll
      for (int r = 0; r < 4; r += 2) {
        float v0 = fmaxf(acc[rt][nt][r] + bb, 0.f);
        float v1 = fmaxf(acc[rt][nt][r + 1] + bb, 0.f);
        uint32_t pk = cvtpk_bf16(v0, v1);
        h[rt * 16 + g * 4 + r][nt * 16 + l15]     = (ushort)(pk & 0xffffu);
        h[rt * 16 + g * 4 + r + 1][nt * 16 + l15] = (ushort)(pk >> 16);
      }
  }

  // ================= GEMM2: e_out = h1 @ ew2 + eb2 =================
#pragma unroll
  for (int rt = 0; rt < RT; ++rt)
#pragma unroll
    for (int nt = 0; nt < 8; ++nt) acc[rt][nt] = zero4;
#pragma unroll
  for (int ks = 0; ks < 4; ++ks) {
    short8 a[RT];
#pragma unroll
    for (int rt = 0; rt < RT; ++rt)
      a[rt] = *reinterpret_cast<const short8*>(&h[rt * 16 + l15][ks * 32 + kg]);
    mm_step(g2 + ks * 4096, lane, a, acc);
  }
  // epilogue 2: store new_edge_attr (fp32, exact) + bf16 copy back to LDS for GEMM3
#pragma unroll
  for (int nt = 0; nt < 8; ++nt) {
    float bb = eb2[nt * 16 + l15];
#pragma unroll
    for (int rt = 0; rt < RT; ++rt) {
      float v[4];
#pragma unroll
      for (int r = 0; r < 4; ++r) {
        v[r] = acc[rt][nt][r] + bb;
        int erow = base + rt * 16 + g * 4 + r;
        out_e[(size_t)erow * CH + nt * 16 + l15] = v[r];
      }
#pragma unroll
      for (int r = 0; r < 4; r += 2) {
        uint32_t pk = cvtpk_bf16(v[r], v[r + 1]);
        h[rt * 16 + g * 4 + r][nt * 16 + l15]     = (ushort)(pk & 0xffffu);
        h[rt * 16 + g * 4 + r + 1][nt * 16 + l15] = (ushort)(pk >> 16);
      }
    }
  }

  // ================= GEMM3: h2 = relu([x[col]|e_out] @ nw1 + nb1) =================
#pragma unroll
  for (int rt = 0; rt < RT; ++rt)
#pragma unroll
    for (int nt = 0; nt < 8; ++nt) acc[rt][nt] = zero4;
#pragma unroll
  for (int ks = 0; ks < 4; ++ks) {               // k 0..127: x[col]
    short8 a[RT];
#pragma unroll
    for (int rt = 0; rt < RT; ++rt)
      a[rt] = *reinterpret_cast<const short8*>(xb + colA[rt] * CH + ks * 32 + kg);
    mm_step(g3 + ks * 4096, lane, a, acc);
  }
#pragma unroll
  for (int ks = 4; ks < 8; ++ks) {               // k 128..255: e_out from LDS
    short8 a[RT];
#pragma unroll
    for (int rt = 0; rt < RT; ++rt)
      a[rt] = *reinterpret_cast<const short8*>(&h[rt * 16 + l15][(ks - 4) * 32 + kg]);
    mm_step(g3 + ks * 4096, lane, a, acc);
  }
  // epilogue 3 -> LDS
#pragma unroll
  for (int nt = 0; nt < 8; ++nt) {
    float bb = nb1[nt * 16 + l15];
#pragma unroll
    for (int rt = 0; rt < RT; ++rt)
#pragma unroll
      for (int r = 0; r < 4; r += 2) {
        float v0 = fmaxf(acc[rt][nt][r] + bb, 0.f);
        float v1 = fmaxf(acc[rt][nt][r + 1] + bb, 0.f);
        uint32_t pk = cvtpk_bf16(v0, v1);
        h[rt * 16 + g * 4 + r][nt * 16 + l15]     = (ushort)(pk & 0xffffu);
        h[rt * 16 + g * 4 + r + 1][nt * 16 + l15] = (ushort)(pk >> 16);
      }
  }

  // ================= GEMM4: msg = h2 @ nw2 + nb2 -> LDS -> coalesced bf16 stores =================
#pragma unroll
  for (int rt = 0; rt < RT; ++rt)
#pragma unroll
    for (int nt = 0; nt < 8; ++nt) acc[rt][nt] = zero4;
#pragma unroll
  for (int ks = 0; ks < 4; ++ks) {
    short8 a[RT];
#pragma unroll
    for (int rt = 0; rt < RT; ++rt)
      a[rt] = *reinterpret_cast<const short8*>(&h[rt * 16 + l15][ks * 32 + kg]);
    mm_step(g4 + ks * 4096, lane, a, acc);
  }
#pragma unroll
  for (int nt = 0; nt < 8; ++nt) {
    float bb = nb2[nt * 16 + l15];
#pragma unroll
    for (int rt = 0; rt < RT; ++rt)
#pragma unroll
      for (int r = 0; r < 4; r += 2) {
        uint32_t pk = cvtpk_bf16(acc[rt][nt][r] + bb, acc[rt][nt][r + 1] + bb);
        h[rt * 16 + g * 4 + r][nt * 16 + l15]     = (ushort)(pk & 0xffffu);
        h[rt * 16 + g * 4 + r + 1][nt * 16 + l15] = (ushort)(pk >> 16);
      }
  }
  // coalesced msg stores: 12 iters x (1 ds_read_b128 + 1 global_store_dwordx4)
#pragma unroll
  for (int it = 0; it < RT * 4; ++it) {
    int row = it * 4 + (lane >> 4);
    int col = l15 * 8;
    short8 v = *reinterpret_cast<const short8*>(&h[row][col]);
    *reinterpret_cast<short8*>(msg + (size_t)(base + row) * CH + col) = v;
  }
}

// scatter-mean via CSR: one wave per node, fp32 accumulate, no atomics.
__global__ __launch_bounds__(256) void reduce_k(const ushort* __restrict__ msg,
    const unsigned* __restrict__ cnt, const unsigned* __restrict__ start,
    const unsigned* __restrict__ eidx, float* __restrict__ out_x) {
  int w = blockIdx.x * 4 + (threadIdx.x >> 6);
  if (w >= NN) return;
  int lane = threadIdx.x & 63;
  unsigned deg = cnt[w], s = start[w];
  float a0 = 0.f, a1 = 0.f;
#pragma unroll 4
  for (unsigned j = 0; j < deg; ++j) {
    unsigned e = eidx[s + j];
    uint32_t pk = *reinterpret_cast<const uint32_t*>(msg + (size_t)e * CH + lane * 2);
    a0 += bf2f(pk & 0xffffu);
    a1 += bf2f(pk >> 16);
  }
  float inv = 1.0f / fmaxf((float)deg, 1.0f);
  float2 o; o.x = a0 * inv; o.y = a1 * inv;
  *reinterpret_cast<float2*>(out_x + (size_t)w * CH + lane * 2) = o;
}

extern "C" void kernel_launch(void* const* d_in, const int* in_sizes, int n_in,
                              void* d_out, int out_size, void* d_ws, size_t ws_size,
                              hipStream_t stream) {
  const float* x   = (const float*)d_in[0];
  const int*   ei  = (const int*)d_in[1];
  const float* ea  = (const float*)d_in[2];
  const float* ew1 = (const float*)d_in[3];
  const float* eb1 = (const float*)d_in[4];
  const float* ew2 = (const float*)d_in[5];
  const float* eb2 = (const float*)d_in[6];
  const float* nw1 = (const float*)d_in[7];
  const float* nb1 = (const float*)d_in[8];
  const float* nw2 = (const float*)d_in[9];
  const float* nb2 = (const float*)d_in[10];

  float* out_x = (float*)d_out;                          // [NN][CH]
  float* out_e = (float*)d_out + (size_t)NN * CH;        // [NE][CH]

  // ws layout: msg bf16 [NE][CH] @0 | wB @153.6M | xb | cnt | start | cursor | eidx
  char* wsb = (char*)d_ws;
  ushort*   msg    = (ushort*)wsb;                                   // 153,600,000 B
  ushort*   wB     = (ushort*)(wsb + 153600000);                     //     229,376 B
  ushort*   xb     = (ushort*)(wsb + 153829376);                     //  12,800,000 B
  unsigned* cnt    = (unsigned*)(wsb + 166629376);                   //     200,000 B
  unsigned* start  = (unsigned*)(wsb + 166829376);                   //     200,000 B
  unsigned* cursor = (unsigned*)(wsb + 167029376);                   //     200,000 B
  unsigned* eidx   = (unsigned*)(wsb + 167229376);                   //   2,400,000 B

  hipMemsetAsync(cnt, 0, (size_t)NN * sizeof(unsigned), stream);
  hipMemsetAsync(cursor, 0, (size_t)NN * sizeof(unsigned), stream);

  prep_frag_k<<<448, 256, 0, stream>>>(ew1, ew2, nw1, nw2, wB);
  convert_x_k<<<(NN * CH / 4 + 255) / 256, 256, 0, stream>>>(x, xb);
  histogram_k<<<(NE + 255) / 256, 256, 0, stream>>>(ei, cnt);
  scan_k<<<1, 1024, 0, stream>>>(cnt, start);
  scatter_k<<<(NE + 255) / 256, 256, 0, stream>>>(ei, start, cursor, eidx);

  int wave_tiles = NE / (RT * 16);                       // 12500
  fused_k<<<(wave_tiles + 3) / 4, 256, 0, stream>>>(ei, ea, wB, eb1, eb2, nb1, nb2, xb, msg, out_e);

  reduce_k<<<(NN + 3) / 4, 256, 0, stream>>>(msg, cnt, start, eidx, out_x);
}

// Round 6
// 484.002 us; speedup vs baseline: 1.8556x; 1.3268x over previous
//
#include <hip/hip_runtime.h>
#include <stdint.h>

#define NN 50000
#define NE 600000
#define CH 128
#define RT 2                      // row-tiles (of 16 edges) per wave -> 32 edges/wave
#define EPB 128                   // edges per block (4 waves x 32)

typedef __attribute__((ext_vector_type(8))) short short8;   // 8 bf16
typedef __attribute__((ext_vector_type(4))) float f32x4;
typedef __attribute__((ext_vector_type(4))) uint32_t u32x4;

__device__ __forceinline__ ushort f2bf(float f) {
  union { float f; uint32_t u; } v; v.f = f;
  uint32_t u = v.u;
  return (ushort)((u + 0x7FFFu + ((u >> 16) & 1u)) >> 16);  // RNE, inputs finite
}
__device__ __forceinline__ float bf2f(uint32_t u16) {
  union { uint32_t u; float f; } t; t.u = u16 << 16; return t.f;
}
// pack two f32 -> two bf16 (RNE) in ONE VALU op
__device__ __forceinline__ uint32_t cvtpk_bf16(float a, float b) {
  uint32_t r;
  asm("v_cvt_pk_bf16_f32 %0, %1, %2" : "=v"(r) : "v"(a), "v"(b));
  return r;
}

// ---- prep: pack weights into exact MFMA-fragment order, bf16 ----
// wB layout (ushort): per GEMM region, element ((ks*8+nt)*512 + lane*8 + i)
//   = W[k = ks*32 + (lane>>4)*8 + i][n = nt*16 + (lane&15)]  (all W are [K][128])
// regions: G1 ew1 @0 (12 ks), G2 ew2 @49152 (4 ks), G3 nw1 @65536 (8 ks), G4 nw2 @98304 (4 ks)
__global__ void prep_frag_k(const float* __restrict__ ew1, const float* __restrict__ ew2,
                            const float* __restrict__ nw1, const float* __restrict__ nw2,
                            ushort* __restrict__ wB) {
  int idx = blockIdx.x * 256 + threadIdx.x;
  if (idx >= 114688) return;
  const float* src; int local;
  if (idx < 49152)      { src = ew1; local = idx; }
  else if (idx < 65536) { src = ew2; local = idx - 49152; }
  else if (idx < 98304) { src = nw1; local = idx - 65536; }
  else                  { src = nw2; local = idx - 98304; }
  int ks   = local >> 12;
  int rem  = local & 4095;
  int nt   = rem >> 9;
  int t    = rem & 511;
  int lane = t >> 3, i = t & 7;
  int k = ks * 32 + (lane >> 4) * 8 + i;
  int n = nt * 16 + (lane & 15);
  wB[idx] = f2bf(src[k * 128 + n]);
}

__global__ void convert_x_k(const float* __restrict__ x, ushort* __restrict__ xb) {
  int i = blockIdx.x * 256 + threadIdx.x;          // over NN*CH/4 float4s
  if (i >= NN * CH / 4) return;
  const float4 f = reinterpret_cast<const float4*>(x)[i];
  ushort4 r;
  r.x = f2bf(f.x); r.y = f2bf(f.y); r.z = f2bf(f.z); r.w = f2bf(f.w);
  reinterpret_cast<ushort4*>(xb)[i] = r;
}

__global__ void histogram_k(const int* __restrict__ ei, unsigned* __restrict__ cnt) {
  int e = blockIdx.x * 256 + threadIdx.x;
  if (e < NE) atomicAdd(&cnt[ei[e]], 1u);
}

// single-block exclusive prefix sum over cnt[NN] -> start[NN]
__global__ void scan_k(const unsigned* __restrict__ cnt, unsigned* __restrict__ start) {
  __shared__ unsigned s[1024];
  const int CHUNK = (NN + 1023) / 1024;            // 49
  int t = threadIdx.x;
  int lo = t * CHUNK, hi = lo + CHUNK < NN ? lo + CHUNK : NN;
  unsigned sum = 0;
  for (int i = lo; i < hi; ++i) sum += cnt[i];
  s[t] = sum;
  __syncthreads();
  for (int off = 1; off < 1024; off <<= 1) {       // Hillis-Steele inclusive
    unsigned v = (t >= off) ? s[t - off] : 0u;
    __syncthreads();
    s[t] += v;
    __syncthreads();
  }
  unsigned run = t ? s[t - 1] : 0u;
  for (int i = lo; i < hi; ++i) { start[i] = run; run += cnt[i]; }
}

// per-edge CSR destination slot: dest[e] = start[row] + rank  (msg written directly in CSR order)
__global__ void dest_k(const int* __restrict__ ei, const unsigned* __restrict__ start,
                       unsigned* __restrict__ cursor, unsigned* __restrict__ dest) {
  int e = blockIdx.x * 256 + threadIdx.x;
  if (e < NE) {
    int r = ei[e];
    dest[e] = start[r] + atomicAdd(&cursor[r], 1u);
  }
}

// one MFMA k-step, B fragments from block-shared LDS (conflict-free lane-linear b128)
__device__ __forceinline__ void mm_step_l(const ushort* Bc, int ksl, int lane,
                                          const short8 a[RT], f32x4 acc[RT][8]) {
#pragma unroll
  for (int nt = 0; nt < 8; ++nt) {
    short8 b = *reinterpret_cast<const short8*>(Bc + (ksl * 8 + nt) * 512 + lane * 8);
#pragma unroll
    for (int rt = 0; rt < RT; ++rt)
      acc[rt][nt] = __builtin_amdgcn_mfma_f32_16x16x32_bf16(a[rt], b, acc[rt][nt], 0, 0, 0);
  }
}

// Fused edge-MLP + node-MLP. Block = 4 waves x 32 edges = 128 edges.
// Weight fragments staged once per block into LDS in 32 KB chunks (4 k-steps),
// shared by all 4 waves -> 4x less B traffic through TA/L1.
// All threads run uniform control flow (clamped tail) so __syncthreads is safe.
__global__ __launch_bounds__(256, 2) void fused_k(
    const int* __restrict__ ei, const float* __restrict__ edge_attr,
    const ushort* __restrict__ wB,
    const float* __restrict__ eb1, const float* __restrict__ eb2,
    const float* __restrict__ nb1, const float* __restrict__ nb2,
    const ushort* __restrict__ xb, const unsigned* __restrict__ dest,
    ushort* __restrict__ msg, float* __restrict__ out_e)
{
  __shared__ ushort hbuf[4][RT * 16][136];   // 34,816 B
  __shared__ ushort Bc[4 * 8 * 512];         // 32,768 B  (4 ks x 8 nt x 1KB)
  const int lane = threadIdx.x & 63;
  const int widx = threadIdx.x >> 6;
  const int wbase = blockIdx.x * EPB + widx * (RT * 16);
  const int l15 = lane & 15;
  const int g = lane >> 4;
  const int kg = g * 8;
  ushort (*h)[136] = hbuf[widx];

  const ushort* g1 = wB;            // 12 ks
  const ushort* g2 = wB + 49152;    // 4 ks
  const ushort* g3 = wB + 65536;    // 8 ks
  const ushort* g4 = wB + 98304;    // 4 ks

  // stage one 32KB chunk (4 ks x 8 nt) of fragment-packed B into LDS, cooperatively
  auto stagechunk = [&](const ushort* wphase, int ks0) {
    __syncthreads();                               // all waves done reading Bc
    short8 tmp[8];
#pragma unroll
    for (int j = 0; j < 8; ++j) {
      int p = widx * 8 + j;
      tmp[j] = *reinterpret_cast<const short8*>(wphase + (size_t)(ks0 * 8 + p) * 512 + lane * 8);
    }
#pragma unroll
    for (int j = 0; j < 8; ++j) {
      int p = widx * 8 + j;
      *reinterpret_cast<short8*>(Bc + p * 512 + lane * 8) = tmp[j];
    }
    __syncthreads();                               // Bc visible to all waves
  };

  int rowA[RT], colA[RT], eAc[RT];
#pragma unroll
  for (int rt = 0; rt < RT; ++rt) {
    int e = wbase + rt * 16 + l15;
    eAc[rt] = e < NE ? e : NE - 1;                 // clamp (tail block), stores guarded below
    rowA[rt] = ei[eAc[rt]];
    colA[rt] = ei[NE + eAc[rt]];
  }

  const f32x4 zero4 = {0.f, 0.f, 0.f, 0.f};
  f32x4 acc[RT][8];

  // ================= GEMM1: h1 = relu([x[row]|x[col]|edge_attr] @ ew1 + eb1) =================
#pragma unroll
  for (int rt = 0; rt < RT; ++rt)
#pragma unroll
    for (int nt = 0; nt < 8; ++nt) acc[rt][nt] = zero4;

  stagechunk(g1, 0);
#pragma unroll
  for (int ksl = 0; ksl < 4; ++ksl) {              // k 0..127: x[row]
    short8 a[RT];
#pragma unroll
    for (int rt = 0; rt < RT; ++rt)
      a[rt] = *reinterpret_cast<const short8*>(xb + rowA[rt] * CH + ksl * 32 + kg);
    mm_step_l(Bc, ksl, lane, a, acc);
  }
  stagechunk(g1, 4);
#pragma unroll
  for (int ksl = 0; ksl < 4; ++ksl) {              // k 128..255: x[col]
    short8 a[RT];
#pragma unroll
    for (int rt = 0; rt < RT; ++rt)
      a[rt] = *reinterpret_cast<const short8*>(xb + colA[rt] * CH + ksl * 32 + kg);
    mm_step_l(Bc, ksl, lane, a, acc);
  }
  stagechunk(g1, 8);
#pragma unroll
  for (int ksl = 0; ksl < 4; ++ksl) {              // k 256..383: edge_attr (fp32 -> bf16 via cvt_pk)
    short8 a[RT];
#pragma unroll
    for (int rt = 0; rt < RT; ++rt) {
      const float* p = edge_attr + (size_t)eAc[rt] * CH + ksl * 32 + kg;
      float4 f0 = *reinterpret_cast<const float4*>(p);
      float4 f1 = *reinterpret_cast<const float4*>(p + 4);
      union { u32x4 u; short8 s; } cv;
      cv.u = (u32x4){ cvtpk_bf16(f0.x, f0.y), cvtpk_bf16(f0.z, f0.w),
                      cvtpk_bf16(f1.x, f1.y), cvtpk_bf16(f1.z, f1.w) };
      a[rt] = cv.s;
    }
    mm_step_l(Bc, ksl, lane, a, acc);
  }
  // epilogue 1 -> LDS (C/D layout: row=(l>>4)*4+reg, col=l&15)
#pragma unroll
  for (int nt = 0; nt < 8; ++nt) {
    float bb = eb1[nt * 16 + l15];
#pragma unroll
    for (int rt = 0; rt < RT; ++rt)
#pragma unroll
      for (int r = 0; r < 4; r += 2) {
        float v0 = fmaxf(acc[rt][nt][r] + bb, 0.f);
        float v1 = fmaxf(acc[rt][nt][r + 1] + bb, 0.f);
        uint32_t pk = cvtpk_bf16(v0, v1);
        h[rt * 16 + g * 4 + r][nt * 16 + l15]     = (ushort)(pk & 0xffffu);
        h[rt * 16 + g * 4 + r + 1][nt * 16 + l15] = (ushort)(pk >> 16);
      }
  }

  // ================= GEMM2: e_out = h1 @ ew2 + eb2 =================
#pragma unroll
  for (int rt = 0; rt < RT; ++rt)
#pragma unroll
    for (int nt = 0; nt < 8; ++nt) acc[rt][nt] = zero4;
  stagechunk(g2, 0);
#pragma unroll
  for (int ksl = 0; ksl < 4; ++ksl) {
    short8 a[RT];
#pragma unroll
    for (int rt = 0; rt < RT; ++rt)
      a[rt] = *reinterpret_cast<const short8*>(&h[rt * 16 + l15][ksl * 32 + kg]);
    mm_step_l(Bc, ksl, lane, a, acc);
  }
  // epilogue 2: store new_edge_attr (fp32, exact) + bf16 copy back to LDS for GEMM3
#pragma unroll
  for (int nt = 0; nt < 8; ++nt) {
    float bb = eb2[nt * 16 + l15];
#pragma unroll
    for (int rt = 0; rt < RT; ++rt) {
      float v[4];
#pragma unroll
      for (int r = 0; r < 4; ++r) {
        v[r] = acc[rt][nt][r] + bb;
        int erow = wbase + rt * 16 + g * 4 + r;
        if (erow < NE) out_e[(size_t)erow * CH + nt * 16 + l15] = v[r];
      }
#pragma unroll
      for (int r = 0; r < 4; r += 2) {
        uint32_t pk = cvtpk_bf16(v[r], v[r + 1]);
        h[rt * 16 + g * 4 + r][nt * 16 + l15]     = (ushort)(pk & 0xffffu);
        h[rt * 16 + g * 4 + r + 1][nt * 16 + l15] = (ushort)(pk >> 16);
      }
    }
  }

  // ================= GEMM3: h2 = relu([x[col]|e_out] @ nw1 + nb1) =================
#pragma unroll
  for (int rt = 0; rt < RT; ++rt)
#pragma unroll
    for (int nt = 0; nt < 8; ++nt) acc[rt][nt] = zero4;
  stagechunk(g3, 0);
#pragma unroll
  for (int ksl = 0; ksl < 4; ++ksl) {              // k 0..127: x[col]
    short8 a[RT];
#pragma unroll
    for (int rt = 0; rt < RT; ++rt)
      a[rt] = *reinterpret_cast<const short8*>(xb + colA[rt] * CH + ksl * 32 + kg);
    mm_step_l(Bc, ksl, lane, a, acc);
  }
  stagechunk(g3, 4);
#pragma unroll
  for (int ksl = 0; ksl < 4; ++ksl) {              // k 128..255: e_out from LDS
    short8 a[RT];
#pragma unroll
    for (int rt = 0; rt < RT; ++rt)
      a[rt] = *reinterpret_cast<const short8*>(&h[rt * 16 + l15][ksl * 32 + kg]);
    mm_step_l(Bc, ksl, lane, a, acc);
  }
  // epilogue 3 -> LDS
#pragma unroll
  for (int nt = 0; nt < 8; ++nt) {
    float bb = nb1[nt * 16 + l15];
#pragma unroll
    for (int rt = 0; rt < RT; ++rt)
#pragma unroll
      for (int r = 0; r < 4; r += 2) {
        float v0 = fmaxf(acc[rt][nt][r] + bb, 0.f);
        float v1 = fmaxf(acc[rt][nt][r + 1] + bb, 0.f);
        uint32_t pk = cvtpk_bf16(v0, v1);
        h[rt * 16 + g * 4 + r][nt * 16 + l15]     = (ushort)(pk & 0xffffu);
        h[rt * 16 + g * 4 + r + 1][nt * 16 + l15] = (ushort)(pk >> 16);
      }
  }

  // ================= GEMM4: msg = h2 @ nw2 + nb2 -> LDS -> coalesced CSR-placed stores =================
#pragma unroll
  for (int rt = 0; rt < RT; ++rt)
#pragma unroll
    for (int nt = 0; nt < 8; ++nt) acc[rt][nt] = zero4;
  stagechunk(g4, 0);
#pragma unroll
  for (int ksl = 0; ksl < 4; ++ksl) {
    short8 a[RT];
#pragma unroll
    for (int rt = 0; rt < RT; ++rt)
      a[rt] = *reinterpret_cast<const short8*>(&h[rt * 16 + l15][ksl * 32 + kg]);
    mm_step_l(Bc, ksl, lane, a, acc);
  }
#pragma unroll
  for (int nt = 0; nt < 8; ++nt) {
    float bb = nb2[nt * 16 + l15];
#pragma unroll
    for (int rt = 0; rt < RT; ++rt)
#pragma unroll
      for (int r = 0; r < 4; r += 2) {
        uint32_t pk = cvtpk_bf16(acc[rt][nt][r] + bb, acc[rt][nt][r + 1] + bb);
        h[rt * 16 + g * 4 + r][nt * 16 + l15]     = (ushort)(pk & 0xffffu);
        h[rt * 16 + g * 4 + r + 1][nt * 16 + l15] = (ushort)(pk >> 16);
      }
  }
  // msg stores: dwordx4, placed directly at CSR slot dest[e] (reduce_k streams them)
#pragma unroll
  for (int it = 0; it < RT * 4; ++it) {
    int row = it * 4 + (lane >> 4);
    int er = wbase + row;
    int col = l15 * 8;
    short8 v = *reinterpret_cast<const short8*>(&h[row][col]);
    if (er < NE) {
      unsigned dp = dest[er];
      *reinterpret_cast<short8*>(msg + (size_t)dp * CH + col) = v;
    }
  }
}

// scatter-mean: msg already in CSR order -> fully coalesced streaming read, no atomics.
__global__ __launch_bounds__(256) void reduce_k(const ushort* __restrict__ msg,
    const unsigned* __restrict__ cnt, const unsigned* __restrict__ start,
    float* __restrict__ out_x) {
  int w = blockIdx.x * 4 + (threadIdx.x >> 6);
  if (w >= NN) return;
  int lane = threadIdx.x & 63;
  unsigned deg = cnt[w], s = start[w];
  float a0 = 0.f, a1 = 0.f;
#pragma unroll 4
  for (unsigned j = 0; j < deg; ++j) {
    uint32_t pk = *reinterpret_cast<const uint32_t*>(msg + (size_t)(s + j) * CH + lane * 2);
    a0 += bf2f(pk & 0xffffu);
    a1 += bf2f(pk >> 16);
  }
  float inv = 1.0f / fmaxf((float)deg, 1.0f);
  float2 o; o.x = a0 * inv; o.y = a1 * inv;
  *reinterpret_cast<float2*>(out_x + (size_t)w * CH + lane * 2) = o;
}

extern "C" void kernel_launch(void* const* d_in, const int* in_sizes, int n_in,
                              void* d_out, int out_size, void* d_ws, size_t ws_size,
                              hipStream_t stream) {
  const float* x   = (const float*)d_in[0];
  const int*   ei  = (const int*)d_in[1];
  const float* ea  = (const float*)d_in[2];
  const float* ew1 = (const float*)d_in[3];
  const float* eb1 = (const float*)d_in[4];
  const float* ew2 = (const float*)d_in[5];
  const float* eb2 = (const float*)d_in[6];
  const float* nw1 = (const float*)d_in[7];
  const float* nb1 = (const float*)d_in[8];
  const float* nw2 = (const float*)d_in[9];
  const float* nb2 = (const float*)d_in[10];

  float* out_x = (float*)d_out;                          // [NN][CH]
  float* out_e = (float*)d_out + (size_t)NN * CH;        // [NE][CH]

  // ws layout: msg bf16 [NE][CH] @0 | wB @153.6M | xb | cnt | start | cursor | dest
  char* wsb = (char*)d_ws;
  ushort*   msg    = (ushort*)wsb;                                   // 153,600,000 B
  ushort*   wB     = (ushort*)(wsb + 153600000);                     //     229,376 B
  ushort*   xb     = (ushort*)(wsb + 153829376);                     //  12,800,000 B
  unsigned* cnt    = (unsigned*)(wsb + 166629376);                   //     200,000 B
  unsigned* start  = (unsigned*)(wsb + 166829376);                   //     200,000 B
  unsigned* cursor = (unsigned*)(wsb + 167029376);                   //     200,000 B
  unsigned* dest   = (unsigned*)(wsb + 167229376);                   //   2,400,000 B

  hipMemsetAsync(cnt, 0, (size_t)NN * sizeof(unsigned), stream);
  hipMemsetAsync(cursor, 0, (size_t)NN * sizeof(unsigned), stream);

  prep_frag_k<<<448, 256, 0, stream>>>(ew1, ew2, nw1, nw2, wB);
  convert_x_k<<<(NN * CH / 4 + 255) / 256, 256, 0, stream>>>(x, xb);
  histogram_k<<<(NE + 255) / 256, 256, 0, stream>>>(ei, cnt);
  scan_k<<<1, 1024, 0, stream>>>(cnt, start);
  dest_k<<<(NE + 255) / 256, 256, 0, stream>>>(ei, start, cursor, dest);

  int nblk = (NE + EPB - 1) / EPB;                       // 4688
  fused_k<<<nblk, 256, 0, stream>>>(ei, ea, wB, eb1, eb2, nb1, nb2, xb, dest, msg, out_e);

  reduce_k<<<(NN + 3) / 4, 256, 0, stream>>>(msg, cnt, start, out_x);
}

// Round 7
// 449.063 us; speedup vs baseline: 1.9999x; 1.0778x over previous
//
#include <hip/hip_runtime.h>
#include <stdint.h>

#define NN 50000
#define NE 600000
#define CH 128
#define RT 2                      // row-tiles (of 16 edges) per wave -> 32 edges/wave
#define EPB 128                   // edges per block (4 waves x 32)

typedef __attribute__((ext_vector_type(8))) short short8;   // 8 bf16
typedef __attribute__((ext_vector_type(4))) float f32x4;
typedef __attribute__((ext_vector_type(4))) uint32_t u32x4;

__device__ __forceinline__ ushort f2bf(float f) {
  union { float f; uint32_t u; } v; v.f = f;
  uint32_t u = v.u;
  return (ushort)((u + 0x7FFFu + ((u >> 16) & 1u)) >> 16);  // RNE, inputs finite
}
__device__ __forceinline__ float bf2f(uint32_t u16) {
  union { uint32_t u; float f; } t; t.u = u16 << 16; return t.f;
}
__device__ __forceinline__ uint32_t cvtpk_bf16(float a, float b) {
  uint32_t r;
  asm("v_cvt_pk_bf16_f32 %0, %1, %2" : "=v"(r) : "v"(a), "v"(b));
  return r;
}

// ---- prep: pack weights into exact MFMA-fragment order, bf16 ----
// wB layout (ushort): GLOBAL PHASE stream ph=0..27, element (ph*4096 + nt*512 + lane*8 + i)
//   = W[k = ks*32 + (lane>>4)*8 + i][n = nt*16 + (lane&15)]
// phases: 0-11 ew1, 12-15 ew2, 16-23 nw1, 24-27 nw2 (regions contiguous)
__global__ void prep_frag_k(const float* __restrict__ ew1, const float* __restrict__ ew2,
                            const float* __restrict__ nw1, const float* __restrict__ nw2,
                            ushort* __restrict__ wB) {
  int idx = blockIdx.x * 256 + threadIdx.x;
  if (idx >= 114688) return;
  const float* src; int local;
  if (idx < 49152)      { src = ew1; local = idx; }
  else if (idx < 65536) { src = ew2; local = idx - 49152; }
  else if (idx < 98304) { src = nw1; local = idx - 65536; }
  else                  { src = nw2; local = idx - 98304; }
  int ks   = local >> 12;
  int rem  = local & 4095;
  int nt   = rem >> 9;
  int t    = rem & 511;
  int lane = t >> 3, i = t & 7;
  int k = ks * 32 + (lane >> 4) * 8 + i;
  int n = nt * 16 + (lane & 15);
  wB[idx] = f2bf(src[k * 128 + n]);
}

__global__ void convert_x_k(const float* __restrict__ x, ushort* __restrict__ xb) {
  int i = blockIdx.x * 256 + threadIdx.x;
  if (i >= NN * CH / 4) return;
  const float4 f = reinterpret_cast<const float4*>(x)[i];
  ushort4 r;
  r.x = f2bf(f.x); r.y = f2bf(f.y); r.z = f2bf(f.z); r.w = f2bf(f.w);
  reinterpret_cast<ushort4*>(xb)[i] = r;
}

// histogram + per-edge rank in one pass
__global__ void rank_k(const int* __restrict__ ei, unsigned* __restrict__ cnt,
                       unsigned* __restrict__ rank) {
  int e = blockIdx.x * 256 + threadIdx.x;
  if (e < NE) rank[e] = atomicAdd(&cnt[ei[e]], 1u);
}

// single-block exclusive prefix sum over cnt[NN] -> start[NN]
__global__ void scan_k(const unsigned* __restrict__ cnt, unsigned* __restrict__ start) {
  __shared__ unsigned s[1024];
  const int CHUNK = (NN + 1023) / 1024;            // 49
  int t = threadIdx.x;
  int lo = t * CHUNK, hi = lo + CHUNK < NN ? lo + CHUNK : NN;
  unsigned sum = 0;
  for (int i = lo; i < hi; ++i) sum += cnt[i];
  s[t] = sum;
  __syncthreads();
  for (int off = 1; off < 1024; off <<= 1) {
    unsigned v = (t >= off) ? s[t - off] : 0u;
    __syncthreads();
    s[t] += v;
    __syncthreads();
  }
  unsigned run = t ? s[t - 1] : 0u;
  for (int i = lo; i < hi; ++i) { start[i] = run; run += cnt[i]; }
}

// dest[e] = start[row] + rank[e]  (contention-free streaming)
__global__ void dest_k(const int* __restrict__ ei, const unsigned* __restrict__ start,
                       const unsigned* __restrict__ rank, unsigned* __restrict__ dest) {
  int e = blockIdx.x * 256 + threadIdx.x;
  if (e < NE) dest[e] = start[ei[e]] + rank[e];
}

// 8 nt-tiles x RT row-tiles of MFMA from one staged LDS phase buffer
__device__ __forceinline__ void mm8(const ushort* Bcbuf, int lane,
                                    const short8 a[RT], f32x4 acc[RT][8]) {
#pragma unroll
  for (int nt = 0; nt < 8; ++nt) {
    short8 b = *reinterpret_cast<const short8*>(Bcbuf + nt * 512 + lane * 8);
#pragma unroll
    for (int rt = 0; rt < RT; ++rt)
      acc[rt][nt] = __builtin_amdgcn_mfma_f32_16x16x32_bf16(a[rt], b, acc[rt][nt], 0, 0, 0);
  }
}

// Fused edge-MLP + node-MLP. Block = 4 waves x 32 edges.
// Weights stream through a DOUBLE-BUFFERED 8KB LDS phase pipeline (28 phases,
// 1 barrier each); loads issued one phase ahead, hidden under MFMA.
// LDS = 34.8 + 16 = 50.7 KB -> 3 blocks/CU.
__global__ __launch_bounds__(256, 3) void fused_k(
    const int* __restrict__ ei, const float* __restrict__ edge_attr,
    const ushort* __restrict__ wB,
    const float* __restrict__ eb1, const float* __restrict__ eb2,
    const float* __restrict__ nb1, const float* __restrict__ nb2,
    const ushort* __restrict__ xb, const unsigned* __restrict__ dest,
    ushort* __restrict__ msg, float* __restrict__ out_e)
{
  __shared__ ushort hbuf[4][RT * 16][136];   // 34,816 B
  __shared__ ushort Bc[2][4096];             // 2 x 8 KB
  const int tid  = threadIdx.x;
  const int lane = tid & 63;
  const int widx = tid >> 6;
  const int wbase = blockIdx.x * EPB + widx * (RT * 16);
  const int l15 = lane & 15;
  const int g = lane >> 4;
  const int kg = g * 8;
  ushort (*h)[136] = hbuf[widx];

  const ushort* wsrc = wB + (size_t)tid * 16;   // + phase*4096
  short8 bt0, bt1;

#define LDB(ph) do { \
    bt0 = *reinterpret_cast<const short8*>(wsrc + (ph) * 4096); \
    bt1 = *reinterpret_cast<const short8*>(wsrc + (ph) * 4096 + 8); \
  } while (0)
#define STB(ph) do { \
    ushort* _d = &Bc[(ph) & 1][tid * 16]; \
    *reinterpret_cast<short8*>(_d) = bt0; \
    *reinterpret_cast<short8*>(_d + 8) = bt1; \
    __syncthreads(); \
  } while (0)

  int rowA[RT], colA[RT], eAc[RT];
#pragma unroll
  for (int rt = 0; rt < RT; ++rt) {
    int e = wbase + rt * 16 + l15;
    eAc[rt] = e < NE ? e : NE - 1;
    rowA[rt] = ei[eAc[rt]];
    colA[rt] = ei[NE + eAc[rt]];
  }

  const f32x4 zero4 = {0.f, 0.f, 0.f, 0.f};
  f32x4 acc[RT][8];

  // =========== GEMM1 (phases 0-11): h1 = relu([x[row]|x[col]|ea] @ ew1 + eb1) ===========
#pragma unroll
  for (int rt = 0; rt < RT; ++rt)
#pragma unroll
    for (int nt = 0; nt < 8; ++nt) acc[rt][nt] = zero4;

  LDB(0);                                     // weights first (vmcnt ordering: STB(0) waits only bt)
  short8 axr[4][RT], axc[4][RT];              // all GEMM1 x-gathers issued up-front
#pragma unroll
  for (int ksl = 0; ksl < 4; ++ksl)
#pragma unroll
    for (int rt = 0; rt < RT; ++rt)
      axr[ksl][rt] = *reinterpret_cast<const short8*>(xb + rowA[rt] * CH + ksl * 32 + kg);
#pragma unroll
  for (int ksl = 0; ksl < 4; ++ksl)
#pragma unroll
    for (int rt = 0; rt < RT; ++rt)
      axc[ksl][rt] = *reinterpret_cast<const short8*>(xb + colA[rt] * CH + ksl * 32 + kg);
  STB(0);

#pragma unroll
  for (int p = 0; p < 4; ++p) {               // x[row]
    LDB(p + 1);
    mm8(Bc[p & 1], lane, axr[p], acc);
    STB(p + 1);
  }
#pragma unroll
  for (int p = 4; p < 8; ++p) {               // x[col]
    LDB(p + 1);
    mm8(Bc[p & 1], lane, axc[p - 4], acc);
    STB(p + 1);
  }
  float4 eaf[4][RT][2];                       // edge_attr raw fp32, all 4 phases
#pragma unroll
  for (int ksl = 0; ksl < 4; ++ksl)
#pragma unroll
    for (int rt = 0; rt < RT; ++rt) {
      const float* pp = edge_attr + (size_t)eAc[rt] * CH + ksl * 32 + kg;
      eaf[ksl][rt][0] = *reinterpret_cast<const float4*>(pp);
      eaf[ksl][rt][1] = *reinterpret_cast<const float4*>(pp + 4);
    }
#pragma unroll
  for (int p = 8; p < 12; ++p) {              // edge_attr (cvt on the fly)
    LDB(p + 1);
    short8 a[RT];
#pragma unroll
    for (int rt = 0; rt < RT; ++rt) {
      float4 f0 = eaf[p - 8][rt][0], f1 = eaf[p - 8][rt][1];
      union { u32x4 u; short8 s; } cv;
      cv.u = (u32x4){ cvtpk_bf16(f0.x, f0.y), cvtpk_bf16(f0.z, f0.w),
                      cvtpk_bf16(f1.x, f1.y), cvtpk_bf16(f1.z, f1.w) };
      a[rt] = cv.s;
    }
    mm8(Bc[p & 1], lane, a, acc);
    STB(p + 1);
  }
  // epilogue 1 -> h (C/D layout: row=(l>>4)*4+reg, col=l&15)
#pragma unroll
  for (int nt = 0; nt < 8; ++nt) {
    float bb = eb1[nt * 16 + l15];
#pragma unroll
    for (int rt = 0; rt < RT; ++rt)
#pragma unroll
      for (int r = 0; r < 4; r += 2) {
        float v0 = fmaxf(acc[rt][nt][r] + bb, 0.f);
        float v1 = fmaxf(acc[rt][nt][r + 1] + bb, 0.f);
        uint32_t pk = cvtpk_bf16(v0, v1);
        h[rt * 16 + g * 4 + r][nt * 16 + l15]     = (ushort)(pk & 0xffffu);
        h[rt * 16 + g * 4 + r + 1][nt * 16 + l15] = (ushort)(pk >> 16);
      }
  }

  // =========== GEMM2 (phases 12-15): e_out = h1 @ ew2 + eb2 ===========
#pragma unroll
  for (int rt = 0; rt < RT; ++rt)
#pragma unroll
    for (int nt = 0; nt < 8; ++nt) acc[rt][nt] = zero4;
#pragma unroll
  for (int p = 12; p < 16; ++p) {
    LDB(p + 1);
    short8 a[RT];
#pragma unroll
    for (int rt = 0; rt < RT; ++rt)
      a[rt] = *reinterpret_cast<const short8*>(&h[rt * 16 + l15][(p - 12) * 32 + kg]);
    mm8(Bc[p & 1], lane, a, acc);
    STB(p + 1);
  }
  // issue GEMM3's x[col] gathers NOW; epilogue-2 VALU hides their latency
  short8 axc2[4][RT];
#pragma unroll
  for (int ksl = 0; ksl < 4; ++ksl)
#pragma unroll
    for (int rt = 0; rt < RT; ++rt)
      axc2[ksl][rt] = *reinterpret_cast<const short8*>(xb + colA[rt] * CH + ksl * 32 + kg);
  // epilogue 2: out_e fp32 (exact) + bf16 back to h for GEMM3
#pragma unroll
  for (int nt = 0; nt < 8; ++nt) {
    float bb = eb2[nt * 16 + l15];
#pragma unroll
    for (int rt = 0; rt < RT; ++rt) {
      float v[4];
#pragma unroll
      for (int r = 0; r < 4; ++r) {
        v[r] = acc[rt][nt][r] + bb;
        int erow = wbase + rt * 16 + g * 4 + r;
        if (erow < NE) out_e[(size_t)erow * CH + nt * 16 + l15] = v[r];
      }
#pragma unroll
      for (int r = 0; r < 4; r += 2) {
        uint32_t pk = cvtpk_bf16(v[r], v[r + 1]);
        h[rt * 16 + g * 4 + r][nt * 16 + l15]     = (ushort)(pk & 0xffffu);
        h[rt * 16 + g * 4 + r + 1][nt * 16 + l15] = (ushort)(pk >> 16);
      }
    }
  }

  // =========== GEMM3 (phases 16-23): h2 = relu([x[col]|e_out] @ nw1 + nb1) ===========
#pragma unroll
  for (int rt = 0; rt < RT; ++rt)
#pragma unroll
    for (int nt = 0; nt < 8; ++nt) acc[rt][nt] = zero4;
#pragma unroll
  for (int p = 16; p < 20; ++p) {             // x[col] (prefetched)
    LDB(p + 1);
    mm8(Bc[p & 1], lane, axc2[p - 16], acc);
    STB(p + 1);
  }
#pragma unroll
  for (int p = 20; p < 24; ++p) {             // e_out from h
    LDB(p + 1);
    short8 a[RT];
#pragma unroll
    for (int rt = 0; rt < RT; ++rt)
      a[rt] = *reinterpret_cast<const short8*>(&h[rt * 16 + l15][(p - 20) * 32 + kg]);
    mm8(Bc[p & 1], lane, a, acc);
    STB(p + 1);
  }
  // epilogue 3 -> h
#pragma unroll
  for (int nt = 0; nt < 8; ++nt) {
    float bb = nb1[nt * 16 + l15];
#pragma unroll
    for (int rt = 0; rt < RT; ++rt)
#pragma unroll
      for (int r = 0; r < 4; r += 2) {
        float v0 = fmaxf(acc[rt][nt][r] + bb, 0.f);
        float v1 = fmaxf(acc[rt][nt][r + 1] + bb, 0.f);
        uint32_t pk = cvtpk_bf16(v0, v1);
        h[rt * 16 + g * 4 + r][nt * 16 + l15]     = (ushort)(pk & 0xffffu);
        h[rt * 16 + g * 4 + r + 1][nt * 16 + l15] = (ushort)(pk >> 16);
      }
  }

  // =========== GEMM4 (phases 24-27): msg = h2 @ nw2 + nb2 ===========
#pragma unroll
  for (int rt = 0; rt < RT; ++rt)
#pragma unroll
    for (int nt = 0; nt < 8; ++nt) acc[rt][nt] = zero4;
#pragma unroll
  for (int p = 24; p < 27; ++p) {
    LDB(p + 1);
    short8 a[RT];
#pragma unroll
    for (int rt = 0; rt < RT; ++rt)
      a[rt] = *reinterpret_cast<const short8*>(&h[rt * 16 + l15][(p - 24) * 32 + kg]);
    mm8(Bc[p & 1], lane, a, acc);
    STB(p + 1);
  }
  {                                            // phase 27: last, no prefetch/barrier
    short8 a[RT];
#pragma unroll
    for (int rt = 0; rt < RT; ++rt)
      a[rt] = *reinterpret_cast<const short8*>(&h[rt * 16 + l15][3 * 32 + kg]);
    mm8(Bc[1], lane, a, acc);
  }
#pragma unroll
  for (int nt = 0; nt < 8; ++nt) {
    float bb = nb2[nt * 16 + l15];
#pragma unroll
    for (int rt = 0; rt < RT; ++rt)
#pragma unroll
      for (int r = 0; r < 4; r += 2) {
        uint32_t pk = cvtpk_bf16(acc[rt][nt][r] + bb, acc[rt][nt][r + 1] + bb);
        h[rt * 16 + g * 4 + r][nt * 16 + l15]     = (ushort)(pk & 0xffffu);
        h[rt * 16 + g * 4 + r + 1][nt * 16 + l15] = (ushort)(pk >> 16);
      }
  }
  // msg stores: dwordx4 at CSR slot dest[e]
#pragma unroll
  for (int it = 0; it < RT * 4; ++it) {
    int row = it * 4 + g;
    int er = wbase + row;
    int col = l15 * 8;
    short8 v = *reinterpret_cast<const short8*>(&h[row][col]);
    if (er < NE) {
      unsigned dp = dest[er];
      *reinterpret_cast<short8*>(msg + (size_t)dp * CH + col) = v;
    }
  }
#undef LDB
#undef STB
}

// scatter-mean: msg in CSR order -> coalesced streaming read, no atomics.
__global__ __launch_bounds__(256) void reduce_k(const ushort* __restrict__ msg,
    const unsigned* __restrict__ cnt, const unsigned* __restrict__ start,
    float* __restrict__ out_x) {
  int w = blockIdx.x * 4 + (threadIdx.x >> 6);
  if (w >= NN) return;
  int lane = threadIdx.x & 63;
  unsigned deg = cnt[w], s = start[w];
  float a0 = 0.f, a1 = 0.f;
#pragma unroll 4
  for (unsigned j = 0; j < deg; ++j) {
    uint32_t pk = *reinterpret_cast<const uint32_t*>(msg + (size_t)(s + j) * CH + lane * 2);
    a0 += bf2f(pk & 0xffffu);
    a1 += bf2f(pk >> 16);
  }
  float inv = 1.0f / fmaxf((float)deg, 1.0f);
  float2 o; o.x = a0 * inv; o.y = a1 * inv;
  *reinterpret_cast<float2*>(out_x + (size_t)w * CH + lane * 2) = o;
}

extern "C" void kernel_launch(void* const* d_in, const int* in_sizes, int n_in,
                              void* d_out, int out_size, void* d_ws, size_t ws_size,
                              hipStream_t stream) {
  const float* x   = (const float*)d_in[0];
  const int*   ei  = (const int*)d_in[1];
  const float* ea  = (const float*)d_in[2];
  const float* ew1 = (const float*)d_in[3];
  const float* eb1 = (const float*)d_in[4];
  const float* ew2 = (const float*)d_in[5];
  const float* eb2 = (const float*)d_in[6];
  const float* nw1 = (const float*)d_in[7];
  const float* nb1 = (const float*)d_in[8];
  const float* nw2 = (const float*)d_in[9];
  const float* nb2 = (const float*)d_in[10];

  float* out_x = (float*)d_out;                          // [NN][CH]
  float* out_e = (float*)d_out + (size_t)NN * CH;        // [NE][CH]

  // ws layout: msg bf16 [NE][CH] @0 | wB | xb | cnt | start | rank | dest
  char* wsb = (char*)d_ws;
  ushort*   msg    = (ushort*)wsb;                                   // 153,600,000 B
  ushort*   wB     = (ushort*)(wsb + 153600000);                     //     229,376 B
  ushort*   xb     = (ushort*)(wsb + 153829376);                     //  12,800,000 B
  unsigned* cnt    = (unsigned*)(wsb + 166629376);                   //     200,000 B
  unsigned* start  = (unsigned*)(wsb + 166829376);                   //     200,000 B
  unsigned* rank   = (unsigned*)(wsb + 167029376);                   //   2,400,000 B
  unsigned* dest   = (unsigned*)(wsb + 169429376);                   //   2,400,000 B

  hipMemsetAsync(cnt, 0, (size_t)NN * sizeof(unsigned), stream);

  prep_frag_k<<<448, 256, 0, stream>>>(ew1, ew2, nw1, nw2, wB);
  convert_x_k<<<(NN * CH / 4 + 255) / 256, 256, 0, stream>>>(x, xb);
  rank_k<<<(NE + 255) / 256, 256, 0, stream>>>(ei, cnt, rank);
  scan_k<<<1, 1024, 0, stream>>>(cnt, start);
  dest_k<<<(NE + 255) / 256, 256, 0, stream>>>(ei, start, rank, dest);

  int nblk = (NE + EPB - 1) / EPB;                       // 4688
  fused_k<<<nblk, 256, 0, stream>>>(ei, ea, wB, eb1, eb2, nb1, nb2, xb, dest, msg, out_e);

  reduce_k<<<(NN + 3) / 4, 256, 0, stream>>>(msg, cnt, start, out_x);
}